// Round 1
// baseline (71.060 us; speedup 1.0000x reference)
//
#include <hip/hip_runtime.h>
#include <stdint.h>

#define IN_F   512
#define N_CTR  2048
#define BATCH  16384

#define BM 128
#define BN 128
#define BK 64

using bf16x8  = __attribute__((ext_vector_type(8))) short;
using f32x4   = __attribute__((ext_vector_type(4))) float;
using ushort8 = __attribute__((ext_vector_type(8))) unsigned short;

typedef const __attribute__((address_space(1))) void* gptr_t;
typedef __attribute__((address_space(3))) void* lptr_t;

static __device__ __forceinline__ unsigned short f2bf(float f) {
    uint32_t u = __builtin_bit_cast(uint32_t, f);
    uint32_t r = u + 0x7fffu + ((u >> 16) & 1u);   // RNE
    return (unsigned short)(r >> 16);
}

// One wave per row: convert f32 row -> bf16 row, emit sum of squares (exact f32).
__global__ void convert_rows(const float* __restrict__ src,
                             unsigned short* __restrict__ dst,
                             float* __restrict__ sq) {
    const int row  = blockIdx.x;
    const int lane = threadIdx.x;              // 64
    const float* rp = src + (size_t)row * IN_F + lane * 8;
    float4 a = *reinterpret_cast<const float4*>(rp);
    float4 b = *reinterpret_cast<const float4*>(rp + 4);
    float ss = a.x*a.x + a.y*a.y + a.z*a.z + a.w*a.w
             + b.x*b.x + b.y*b.y + b.z*b.z + b.w*b.w;
    ushort8 o;
    o[0]=f2bf(a.x); o[1]=f2bf(a.y); o[2]=f2bf(a.z); o[3]=f2bf(a.w);
    o[4]=f2bf(b.x); o[5]=f2bf(b.y); o[6]=f2bf(b.z); o[7]=f2bf(b.w);
    *reinterpret_cast<ushort8*>(dst + (size_t)row * IN_F + lane * 8) = o;
    #pragma unroll
    for (int off = 32; off > 0; off >>= 1) ss += __shfl_down(ss, off);
    if (lane == 0) sq[row] = ss;
}

// 128x128 tile bf16 MFMA GEMM with fused RBF epilogue.
__launch_bounds__(256, 2)
__global__ void rbf_gemm(const unsigned short* __restrict__ xb,
                         const unsigned short* __restrict__ cb,
                         const float* __restrict__ xsq,
                         const float* __restrict__ csq,
                         const float* __restrict__ beta,
                         float* __restrict__ out) {
    __shared__ unsigned short As[BM * BK];   // 16 KB
    __shared__ unsigned short Bs[BN * BK];   // 16 KB

    const int tid  = threadIdx.x;
    const int wid  = tid >> 6;
    const int lane = tid & 63;
    const int wr   = wid >> 1;               // 0..1
    const int wc   = wid & 1;                // 0..1

    const int ntn = N_CTR / BN;              // 16
    const int tm  = blockIdx.x / ntn;
    const int tn  = blockIdx.x % ntn;

    // staging geometry: per wave 4 issues, each issue = 64 lanes x 16B = 8 LDS rows
    const int srow = (wid * 4) * 8 + (lane >> 3);   // +i*8 per issue
    const int scol = (lane & 7) * 8;                // element col
    const unsigned short* gA0 = xb + (size_t)(tm * BM + srow) * IN_F + scol;
    const unsigned short* gB0 = cb + (size_t)(tn * BN + srow) * IN_F + scol;

    f32x4 acc[4][4] = {};

    for (int kt = 0; kt < IN_F / BK; ++kt) {
        const int kbase = kt * BK;
        #pragma unroll
        for (int i = 0; i < 4; ++i) {
            const unsigned short* ga = gA0 + (size_t)(i * 8) * IN_F + kbase;
            const unsigned short* gb = gB0 + (size_t)(i * 8) * IN_F + kbase;
            __builtin_amdgcn_global_load_lds((gptr_t)ga, (lptr_t)(As + (wid * 4 + i) * 512), 16, 0, 0);
            __builtin_amdgcn_global_load_lds((gptr_t)gb, (lptr_t)(Bs + (wid * 4 + i) * 512), 16, 0, 0);
        }
        __syncthreads();

        #pragma unroll
        for (int kk = 0; kk < 2; ++kk) {
            bf16x8 af[4], bfr[4];
            const int kreg = kk * 32 + (lane >> 4) * 8;
            #pragma unroll
            for (int mi = 0; mi < 4; ++mi)
                af[mi] = *reinterpret_cast<const bf16x8*>(
                    &As[(wr * 64 + mi * 16 + (lane & 15)) * BK + kreg]);
            #pragma unroll
            for (int ni = 0; ni < 4; ++ni)
                bfr[ni] = *reinterpret_cast<const bf16x8*>(
                    &Bs[(wc * 64 + ni * 16 + (lane & 15)) * BK + kreg]);
            #pragma unroll
            for (int mi = 0; mi < 4; ++mi)
                #pragma unroll
                for (int ni = 0; ni < 4; ++ni)
                    acc[mi][ni] = __builtin_amdgcn_mfma_f32_16x16x32_bf16(
                        af[mi], bfr[ni], acc[mi][ni], 0, 0, 0);
        }
        __syncthreads();
    }

    // epilogue: out = exp(-beta * (xsq + csq - 2*cross))
    const int row0 = tm * BM + wr * 64;
    const int col0 = tn * BN + wc * 64;
    #pragma unroll
    for (int ni = 0; ni < 4; ++ni) {
        const int col = col0 + ni * 16 + (lane & 15);
        const float bt = beta[col];
        const float cs = csq[col];
        #pragma unroll
        for (int mi = 0; mi < 4; ++mi) {
            #pragma unroll
            for (int j = 0; j < 4; ++j) {
                const int row = row0 + mi * 16 + (lane >> 4) * 4 + j;
                const float d = xsq[row] + cs - 2.0f * acc[mi][ni][j];
                out[(size_t)row * N_CTR + col] = __expf(-bt * d);
            }
        }
    }
}

// Fallback (ws too small): correct f32 path, LDS-staged x row.
__global__ void rbf_naive(const float* __restrict__ x,
                          const float* __restrict__ c,
                          const float* __restrict__ beta,
                          float* __restrict__ out) {
    __shared__ float xs[IN_F];
    const int row = blockIdx.x;
    const int col = blockIdx.y * 128 + threadIdx.x;
    for (int i = threadIdx.x; i < IN_F; i += 128)
        xs[i] = x[(size_t)row * IN_F + i];
    __syncthreads();
    const float* cp = c + (size_t)col * IN_F;
    float d = 0.f;
    #pragma unroll 4
    for (int k = 0; k < IN_F; k += 4) {
        float4 cv = *reinterpret_cast<const float4*>(cp + k);
        float t0 = xs[k + 0] - cv.x;
        float t1 = xs[k + 1] - cv.y;
        float t2 = xs[k + 2] - cv.z;
        float t3 = xs[k + 3] - cv.w;
        d += t0 * t0 + t1 * t1 + t2 * t2 + t3 * t3;
    }
    out[(size_t)row * N_CTR + col] = __expf(-beta[col] * d);
}

extern "C" void kernel_launch(void* const* d_in, const int* in_sizes, int n_in,
                              void* d_out, int out_size, void* d_ws, size_t ws_size,
                              hipStream_t stream) {
    const float* x    = (const float*)d_in[0];
    const float* c    = (const float*)d_in[1];
    const float* beta = (const float*)d_in[2];
    float* out        = (float*)d_out;

    const size_t need = (size_t)BATCH * IN_F * 2 + (size_t)N_CTR * IN_F * 2
                      + (size_t)BATCH * 4 + (size_t)N_CTR * 4;
    if (ws_size >= need) {
        unsigned short* xbuf = (unsigned short*)d_ws;
        unsigned short* cbuf = xbuf + (size_t)BATCH * IN_F;
        float* xsq = (float*)(cbuf + (size_t)N_CTR * IN_F);
        float* csq = xsq + BATCH;
        convert_rows<<<BATCH, 64, 0, stream>>>(x, xbuf, xsq);
        convert_rows<<<N_CTR, 64, 0, stream>>>(c, cbuf, csq);
        rbf_gemm<<<(BATCH / BM) * (N_CTR / BN), 256, 0, stream>>>(
            xbuf, cbuf, xsq, csq, beta, out);
    } else {
        rbf_naive<<<dim3(BATCH, N_CTR / 128), 128, 0, stream>>>(x, c, beta, out);
    }
}